// Round 11
// baseline (92.475 us; speedup 1.0000x reference)
//
#include <hip/hip_runtime.h>

// Morph2D soft rank-order filter:
//   patches(3x3, zero-pad SAME) * se -> sort ascending -> dot softmax(rank)
// x: [32,512,512,1] fp32 -> out same shape.
//
// R11: 8 rows x 4 cols per thread (32 px). Doubles per-wave fixed-cost
// amortization vs R9 (the only lever besides sort-op count that has moved
// exec time). Ternary min3/med3/max3 tableau sort (29 ops), shuffle halo,
// plain __launch_bounds__(256) — forced-occupancy variants spill (R7).

#define HH 512
#define WW 512

#define RFL(x) __int_as_float(__builtin_amdgcn_readfirstlane(__float_as_int(x)))
#define MIN3(a,b,c) fminf(fminf(a,b),c)
#define MAX3(a,b,c) fmaxf(fmaxf(a,b),c)
#define MED3(a,b,c) __builtin_amdgcn_fmed3f(a,b,c)
#define TSORT(a,b,c) { float t0_=MIN3(a,b,c), t1_=MED3(a,b,c), t2_=MAX3(a,b,c); a=t0_; b=t1_; c=t2_; }

__global__ __launch_bounds__(256) void morph2d_kernel(
    const float* __restrict__ x, const float* __restrict__ se9,
    const float* __restrict__ rank, float* __restrict__ out)
{
    // XCD-aware swizzle: contiguous chunk of blocks per XCD
    int nper = gridDim.x >> 3;
    int lb   = (blockIdx.x & 7) * nper + (blockIdx.x >> 3);
    int g    = lb * 256 + threadIdx.x;       // 262,144 total, exact

    int gx = g & 127;             // x-group of 4 px
    int rg = (g >> 7) & 63;       // row-group of 8 rows (wave-uniform)
    int b  = g >> 13;             // batch
    int x4 = gx << 2;
    int y0 = rg << 3;
    int lane = threadIdx.x & 63;

    const float* img = x + (size_t)b * (HH * WW);

    // wave-edge halo lanes: lane 0 loads col x4-1, lane 63 loads col x4+4
    bool eL = (lane == 0)  && (x4 > 0);
    bool eR = (lane == 63) && (x4 + 4 < WW);
    bool eAny = eL || eR;
    int  eoff = eL ? (x4 - 1) : (x4 + 4);

    // ---- issue all global loads: 10 rows (y0-1 .. y0+8) ----
    float4 c[10];
    float  eg[10];
    float  mm[10];
    #pragma unroll
    for (int r = 0; r < 10; ++r) {
        int ry  = y0 - 1 + r;
        int ryc = min(max(ry, 0), HH - 1);
        const float* p = img + ryc * WW;
        c[r]  = *(const float4*)(p + x4);
        eg[r] = eAny ? p[eoff] : 0.f;
        mm[r] = (ry >= 0 && ry < HH) ? 1.f : 0.f;   // only rows 0 and 9 can mask
    }

    // ---- softmax(rank) (1/s folded) + se, scalarized, under load shadow ----
    float w0,w1,w2,w3,w4,w5,w6,w7,w8;
    float s0,s1,s2,s3,s4,s5,s6,s7,s8;
    {
        float e[9]; float s = 0.f;
        #pragma unroll
        for (int i = 0; i < 9; ++i) { e[i] = __expf(rank[i]); s += e[i]; }
        float inv = 1.0f / s;
        w0=RFL(e[0]*inv); w1=RFL(e[1]*inv); w2=RFL(e[2]*inv);
        w3=RFL(e[3]*inv); w4=RFL(e[4]*inv); w5=RFL(e[5]*inv);
        w6=RFL(e[6]*inv); w7=RFL(e[7]*inv); w8=RFL(e[8]*inv);
        s0=RFL(se9[0]); s1=RFL(se9[1]); s2=RFL(se9[2]); s3=RFL(se9[3]);
        s4=RFL(se9[4]); s5=RFL(se9[5]); s6=RFL(se9[6]); s7=RFL(se9[7]); s8=RFL(se9[8]);
    }

    // ---- reconstruct 6-col rows: halos from neighbor lanes ----
    float R[10][6];
    #pragma unroll
    for (int r = 0; r < 10; ++r) {
        float lw = __shfl_up(c[r].w, 1);     // lane i-1's c.w  (col x4-1)
        float rx = __shfl_down(c[r].x, 1);   // lane i+1's c.x  (col x4+4)
        float lf = (lane == 0)  ? eg[r] : lw;   // x4==0 -> eg==0 (zero-pad)
        float rt = (lane == 63) ? eg[r] : rx;   // x4+4==WW -> eg==0
        float m  = mm[r];
        R[r][0] = lf * m;     R[r][1] = c[r].x * m; R[r][2] = c[r].y * m;
        R[r][3] = c[r].z * m; R[r][4] = c[r].w * m; R[r][5] = rt * m;
    }

    // ---- 32 px: se-weight, ternary tableau sort (29 ops), dot ----
    #pragma unroll
    for (int r = 0; r < 8; ++r) {
        float res[4];
        #pragma unroll
        for (int j = 0; j < 4; ++j) {
            float v0 = R[r  ][j]*s0, v1 = R[r  ][j+1]*s1, v2 = R[r  ][j+2]*s2;
            float v3 = R[r+1][j]*s3, v4 = R[r+1][j+1]*s4, v5 = R[r+1][j+2]*s5;
            float v6 = R[r+2][j]*s6, v7 = R[r+2][j+1]*s7, v8 = R[r+2][j+2]*s8;

            TSORT(v0, v1, v2)            // rows
            TSORT(v3, v4, v5)
            TSORT(v6, v7, v8)
            TSORT(v0, v3, v6)            // cols (rows remain sorted)
            TSORT(v1, v4, v7)
            TSORT(v2, v5, v8)
            float r1 = fminf(v1, v3), p = fmaxf(v1, v3);
            float r7 = fmaxf(v5, v7), q = fminf(v5, v7);
            TSORT(v2, v4, v6)            // anti-diagonal; v4 = rank 4
            float r2 = fminf(p, v2), r3 = fmaxf(p, v2);
            float r5 = fminf(q, v6), r6 = fmaxf(q, v6);

            float acc = v0 * w0;
            acc = fmaf(r1, w1, acc);
            acc = fmaf(r2, w2, acc);
            acc = fmaf(r3, w3, acc);
            acc = fmaf(v4, w4, acc);
            acc = fmaf(r5, w5, acc);
            acc = fmaf(r6, w6, acc);
            acc = fmaf(r7, w7, acc);
            acc = fmaf(v8, w8, acc);
            res[j] = acc;
        }
        float4 o = { res[0], res[1], res[2], res[3] };
        *(float4*)(out + (((size_t)b * HH + (y0 + r)) * WW + x4)) = o;
    }
}

extern "C" void kernel_launch(void* const* d_in, const int* in_sizes, int n_in,
                              void* d_out, int out_size, void* d_ws, size_t ws_size,
                              hipStream_t stream) {
    const float* x    = (const float*)d_in[0];
    const float* se   = (const float*)d_in[1];
    const float* rank = (const float*)d_in[2];
    float* out = (float*)d_out;

    const int total_threads = 32 * (HH / 8) * (WW / 4);   // 262,144
    morph2d_kernel<<<total_threads / 256, 256, 0, stream>>>(x, se, rank, out);
}

// Round 12
// 90.377 us; speedup vs baseline: 1.0232x; 1.0232x over previous
//
#include <hip/hip_runtime.h>

// Morph2D soft rank-order filter:
//   patches(3x3, zero-pad SAME) * se -> sort ascending -> dot softmax(rank)
// x: [32,512,512,1] fp32 -> out same shape.
//
// FINAL (revert to R9, best measured: 89.3 us total):
//  - 4x4 px/thread: best fixed-cost amortization point (R11's 8x4 regressed
//    via register pressure; R4's 1x4 paid 4x the per-wave cold-load cost)
//  - ternary min3/med3/max3 tableau 9-sort: 29 ops vs 50-op binary network
//    (R8: -6 us). v_med3_f32 is 1 inst on gfx950.
//  - shuffle halo: 6 dense float4 + 1 two-lane scalar load per row; window
//    edge columns via __shfl_up/__shfl_down (R9: -1 us)
//  - plain __launch_bounds__(256): forcing the occupancy arg (256,4)/(256,8)
//    caps VGPR=64 and spills 800+ MB scratch (R7 probe: 840 MB WRITE_SIZE)
//  - XCD-aware block swizzle for L2 locality

#define HH 512
#define WW 512

#define RFL(x) __int_as_float(__builtin_amdgcn_readfirstlane(__float_as_int(x)))
#define MIN3(a,b,c) fminf(fminf(a,b),c)
#define MAX3(a,b,c) fmaxf(fmaxf(a,b),c)
#define MED3(a,b,c) __builtin_amdgcn_fmed3f(a,b,c)
#define TSORT(a,b,c) { float t0_=MIN3(a,b,c), t1_=MED3(a,b,c), t2_=MAX3(a,b,c); a=t0_; b=t1_; c=t2_; }

__global__ __launch_bounds__(256) void morph2d_kernel(
    const float* __restrict__ x, const float* __restrict__ se9,
    const float* __restrict__ rank, float* __restrict__ out)
{
    // XCD-aware swizzle: contiguous chunk of blocks per XCD
    int nper = gridDim.x >> 3;
    int lb   = (blockIdx.x & 7) * nper + (blockIdx.x >> 3);
    int g    = lb * 256 + threadIdx.x;       // 524,288 total, exact

    int gx = g & 127;             // x-group of 4 px
    int rg = (g >> 7) & 127;      // row-group of 4 rows (wave-uniform)
    int b  = g >> 14;             // batch
    int x4 = gx << 2;
    int y0 = rg << 2;
    int lane = threadIdx.x & 63;

    const float* img = x + (size_t)b * (HH * WW);

    // wave-edge halo lanes: lane 0 loads col x4-1, lane 63 loads col x4+4
    bool eL = (lane == 0)  && (x4 > 0);
    bool eR = (lane == 63) && (x4 + 4 < WW);
    bool eAny = eL || eR;
    int  eoff = eL ? (x4 - 1) : (x4 + 4);

    // ---- issue all global loads (6 float4 + 6 masked scalars) ----
    float4 c[6];
    float  eg[6];
    float  mm[6];
    #pragma unroll
    for (int r = 0; r < 6; ++r) {
        int ry  = y0 - 1 + r;
        int ryc = min(max(ry, 0), HH - 1);
        const float* p = img + ryc * WW;
        c[r]  = *(const float4*)(p + x4);
        eg[r] = eAny ? p[eoff] : 0.f;
        mm[r] = (ry >= 0 && ry < HH) ? 1.f : 0.f;   // only rows 0 and 5 can mask
    }

    // ---- softmax(rank) (1/s folded) + se, scalarized, under load shadow ----
    float w0,w1,w2,w3,w4,w5,w6,w7,w8;
    float s0,s1,s2,s3,s4,s5,s6,s7,s8;
    {
        float e[9]; float s = 0.f;
        #pragma unroll
        for (int i = 0; i < 9; ++i) { e[i] = __expf(rank[i]); s += e[i]; }
        float inv = 1.0f / s;
        w0=RFL(e[0]*inv); w1=RFL(e[1]*inv); w2=RFL(e[2]*inv);
        w3=RFL(e[3]*inv); w4=RFL(e[4]*inv); w5=RFL(e[5]*inv);
        w6=RFL(e[6]*inv); w7=RFL(e[7]*inv); w8=RFL(e[8]*inv);
        s0=RFL(se9[0]); s1=RFL(se9[1]); s2=RFL(se9[2]); s3=RFL(se9[3]);
        s4=RFL(se9[4]); s5=RFL(se9[5]); s6=RFL(se9[6]); s7=RFL(se9[7]); s8=RFL(se9[8]);
    }

    // ---- reconstruct 6-col rows: halos from neighbor lanes ----
    float R[6][6];
    #pragma unroll
    for (int r = 0; r < 6; ++r) {
        float lw = __shfl_up(c[r].w, 1);     // lane i-1's c.w  (col x4-1)
        float rx = __shfl_down(c[r].x, 1);   // lane i+1's c.x  (col x4+4)
        float lf = (lane == 0)  ? eg[r] : lw;   // x4==0 -> eg==0 (zero-pad)
        float rt = (lane == 63) ? eg[r] : rx;   // x4+4==WW -> eg==0
        float m  = mm[r];
        R[r][0] = lf * m;     R[r][1] = c[r].x * m; R[r][2] = c[r].y * m;
        R[r][3] = c[r].z * m; R[r][4] = c[r].w * m; R[r][5] = rt * m;
    }

    // ---- 16 px: se-weight, ternary tableau sort (29 ops), dot ----
    #pragma unroll
    for (int r = 0; r < 4; ++r) {
        float res[4];
        #pragma unroll
        for (int j = 0; j < 4; ++j) {
            float v0 = R[r  ][j]*s0, v1 = R[r  ][j+1]*s1, v2 = R[r  ][j+2]*s2;
            float v3 = R[r+1][j]*s3, v4 = R[r+1][j+1]*s4, v5 = R[r+1][j+2]*s5;
            float v6 = R[r+2][j]*s6, v7 = R[r+2][j+1]*s7, v8 = R[r+2][j+2]*s8;

            TSORT(v0, v1, v2)            // rows
            TSORT(v3, v4, v5)
            TSORT(v6, v7, v8)
            TSORT(v0, v3, v6)            // cols (rows remain sorted)
            TSORT(v1, v4, v7)
            TSORT(v2, v5, v8)
            float r1 = fminf(v1, v3), p = fmaxf(v1, v3);
            float r7 = fmaxf(v5, v7), q = fminf(v5, v7);
            TSORT(v2, v4, v6)            // anti-diagonal; v4 = rank 4
            float r2 = fminf(p, v2), r3 = fmaxf(p, v2);
            float r5 = fminf(q, v6), r6 = fmaxf(q, v6);

            float acc = v0 * w0;
            acc = fmaf(r1, w1, acc);
            acc = fmaf(r2, w2, acc);
            acc = fmaf(r3, w3, acc);
            acc = fmaf(v4, w4, acc);
            acc = fmaf(r5, w5, acc);
            acc = fmaf(r6, w6, acc);
            acc = fmaf(r7, w7, acc);
            acc = fmaf(v8, w8, acc);
            res[j] = acc;
        }
        float4 o = { res[0], res[1], res[2], res[3] };
        *(float4*)(out + (((size_t)b * HH + (y0 + r)) * WW + x4)) = o;
    }
}

extern "C" void kernel_launch(void* const* d_in, const int* in_sizes, int n_in,
                              void* d_out, int out_size, void* d_ws, size_t ws_size,
                              hipStream_t stream) {
    const float* x    = (const float*)d_in[0];
    const float* se   = (const float*)d_in[1];
    const float* rank = (const float*)d_in[2];
    float* out = (float*)d_out;

    const int total_threads = 32 * (HH / 4) * (WW / 4);   // 524,288
    morph2d_kernel<<<total_threads / 256, 256, 0, stream>>>(x, se, rank, out);
}

// Round 13
// 89.048 us; speedup vs baseline: 1.0385x; 1.0149x over previous
//
#include <hip/hip_runtime.h>

// Morph2D soft rank-order filter:
//   patches(3x3, zero-pad SAME) * se -> sort ascending -> dot softmax(rank)
// x: [32,512,512,1] fp32 -> out same shape.
//
// R13 = R9 + exec-masked halo loads. R9's `eAny ? p[eoff] : 0` selects the
// VALUE but still issues the gather for all 64 lanes (16 lines/row). An
// explicit `if (eAny)` branch exec-masks the load so only lanes 0/63 fetch
// (2 lines/row). Everything else identical to the best measured kernel.

#define HH 512
#define WW 512

#define RFL(x) __int_as_float(__builtin_amdgcn_readfirstlane(__float_as_int(x)))
#define MIN3(a,b,c) fminf(fminf(a,b),c)
#define MAX3(a,b,c) fmaxf(fmaxf(a,b),c)
#define MED3(a,b,c) __builtin_amdgcn_fmed3f(a,b,c)
#define TSORT(a,b,c) { float t0_=MIN3(a,b,c), t1_=MED3(a,b,c), t2_=MAX3(a,b,c); a=t0_; b=t1_; c=t2_; }

__global__ __launch_bounds__(256) void morph2d_kernel(
    const float* __restrict__ x, const float* __restrict__ se9,
    const float* __restrict__ rank, float* __restrict__ out)
{
    // XCD-aware swizzle: contiguous chunk of blocks per XCD
    int nper = gridDim.x >> 3;
    int lb   = (blockIdx.x & 7) * nper + (blockIdx.x >> 3);
    int g    = lb * 256 + threadIdx.x;       // 524,288 total, exact

    int gx = g & 127;             // x-group of 4 px
    int rg = (g >> 7) & 127;      // row-group of 4 rows (wave-uniform)
    int b  = g >> 14;             // batch
    int x4 = gx << 2;
    int y0 = rg << 2;
    int lane = threadIdx.x & 63;

    const float* img = x + (size_t)b * (HH * WW);

    // clamped row offsets + y-border masks
    int   rowoff[6];
    float mm[6];
    #pragma unroll
    for (int r = 0; r < 6; ++r) {
        int ry = y0 - 1 + r;
        rowoff[r] = min(max(ry, 0), HH - 1) * WW;
        mm[r]     = (ry >= 0 && ry < HH) ? 1.f : 0.f;   // only rows 0/5 can mask
    }

    // ---- dense loads: 6 x float4, all lanes, perfectly coalesced ----
    float4 c[6];
    #pragma unroll
    for (int r = 0; r < 6; ++r)
        c[r] = *(const float4*)(img + rowoff[r] + x4);

    // ---- halo loads: EXEC-MASKED — only lanes 0 / 63 issue traffic ----
    bool eL = (lane == 0)  && (x4 > 0);
    bool eR = (lane == 63) && (x4 + 4 < WW);
    float eg[6] = {0.f, 0.f, 0.f, 0.f, 0.f, 0.f};   // zero-pad default
    if (eL || eR) {
        int eoff = eL ? (x4 - 1) : (x4 + 4);
        #pragma unroll
        for (int r = 0; r < 6; ++r)
            eg[r] = img[rowoff[r] + eoff];
    }

    // ---- softmax(rank) (1/s folded) + se, scalarized, under load shadow ----
    float w0,w1,w2,w3,w4,w5,w6,w7,w8;
    float s0,s1,s2,s3,s4,s5,s6,s7,s8;
    {
        float e[9]; float s = 0.f;
        #pragma unroll
        for (int i = 0; i < 9; ++i) { e[i] = __expf(rank[i]); s += e[i]; }
        float inv = 1.0f / s;
        w0=RFL(e[0]*inv); w1=RFL(e[1]*inv); w2=RFL(e[2]*inv);
        w3=RFL(e[3]*inv); w4=RFL(e[4]*inv); w5=RFL(e[5]*inv);
        w6=RFL(e[6]*inv); w7=RFL(e[7]*inv); w8=RFL(e[8]*inv);
        s0=RFL(se9[0]); s1=RFL(se9[1]); s2=RFL(se9[2]); s3=RFL(se9[3]);
        s4=RFL(se9[4]); s5=RFL(se9[5]); s6=RFL(se9[6]); s7=RFL(se9[7]); s8=RFL(se9[8]);
    }

    // ---- reconstruct 6-col rows: halos from neighbor lanes ----
    float R[6][6];
    #pragma unroll
    for (int r = 0; r < 6; ++r) {
        float lw = __shfl_up(c[r].w, 1);     // lane i-1's c.w  (col x4-1)
        float rx = __shfl_down(c[r].x, 1);   // lane i+1's c.x  (col x4+4)
        float lf = (lane == 0)  ? eg[r] : lw;   // x4==0 -> eg==0 (zero-pad)
        float rt = (lane == 63) ? eg[r] : rx;   // x4+4==WW -> eg==0
        float m  = mm[r];
        R[r][0] = lf * m;     R[r][1] = c[r].x * m; R[r][2] = c[r].y * m;
        R[r][3] = c[r].z * m; R[r][4] = c[r].w * m; R[r][5] = rt * m;
    }

    // ---- 16 px: se-weight, ternary tableau sort (29 ops), dot ----
    #pragma unroll
    for (int r = 0; r < 4; ++r) {
        float res[4];
        #pragma unroll
        for (int j = 0; j < 4; ++j) {
            float v0 = R[r  ][j]*s0, v1 = R[r  ][j+1]*s1, v2 = R[r  ][j+2]*s2;
            float v3 = R[r+1][j]*s3, v4 = R[r+1][j+1]*s4, v5 = R[r+1][j+2]*s5;
            float v6 = R[r+2][j]*s6, v7 = R[r+2][j+1]*s7, v8 = R[r+2][j+2]*s8;

            TSORT(v0, v1, v2)            // rows
            TSORT(v3, v4, v5)
            TSORT(v6, v7, v8)
            TSORT(v0, v3, v6)            // cols (rows remain sorted)
            TSORT(v1, v4, v7)
            TSORT(v2, v5, v8)
            float r1 = fminf(v1, v3), p = fmaxf(v1, v3);
            float r7 = fmaxf(v5, v7), q = fminf(v5, v7);
            TSORT(v2, v4, v6)            // anti-diagonal; v4 = rank 4
            float r2 = fminf(p, v2), r3 = fmaxf(p, v2);
            float r5 = fminf(q, v6), r6 = fmaxf(q, v6);

            float acc = v0 * w0;
            acc = fmaf(r1, w1, acc);
            acc = fmaf(r2, w2, acc);
            acc = fmaf(r3, w3, acc);
            acc = fmaf(v4, w4, acc);
            acc = fmaf(r5, w5, acc);
            acc = fmaf(r6, w6, acc);
            acc = fmaf(r7, w7, acc);
            acc = fmaf(v8, w8, acc);
            res[j] = acc;
        }
        float4 o = { res[0], res[1], res[2], res[3] };
        *(float4*)(out + (((size_t)b * HH + (y0 + r)) * WW + x4)) = o;
    }
}

extern "C" void kernel_launch(void* const* d_in, const int* in_sizes, int n_in,
                              void* d_out, int out_size, void* d_ws, size_t ws_size,
                              hipStream_t stream) {
    const float* x    = (const float*)d_in[0];
    const float* se   = (const float*)d_in[1];
    const float* rank = (const float*)d_in[2];
    float* out = (float*)d_out;

    const int total_threads = 32 * (HH / 4) * (WW / 4);   // 524,288
    morph2d_kernel<<<total_threads / 256, 256, 0, stream>>>(x, se, rank, out);
}